// Round 1
// baseline (104.273 us; speedup 1.0000x reference)
//
#include <hip/hip_runtime.h>
#include <math.h>

#define TT 10
#define CHN 16
#define HH 16
#define WW 264
#define HW (HH*WW)        // 4224
#define DD (CHN*HW)       // 67584
#define NPAIR 90
#define NCHUNK 33
#define CHUNK (DD/NCHUNK) // 2048
#define NACC 55           // upper-triangular 10x10 pairs

// ---------------- kernel 1: poses -------------------------------------------
// pose(i) for pair (b = i/9, ts = i%9+1):  pose = P[ts-1] - P[b],
// P[k] = fp32 sequential cumsum of dp (matches reference rounding).
__global__ void meta_kernel(const float* __restrict__ dp, float4* __restrict__ meta) {
    int i = threadIdx.x;
    if (i >= NPAIR) return;
    int b  = i / 9;
    int ts = i % 9 + 1;
    float ax = 0.f, ay = 0.f, az = 0.f;
    for (int j = 0; j < ts - 1; ++j) { ax += dp[j*3]; ay += dp[j*3+1]; az += dp[j*3+2]; }
    float bx = 0.f, by = 0.f, bz = 0.f;
    for (int j = 0; j < b; ++j)      { bx += dp[j*3]; by += dp[j*3+1]; bz += dp[j*3+2]; }
    float dx  = ax - bx;
    float dy  = ay - by;
    float yaw = az - bz;
    float c = (float)cos((double)yaw);  // double for correctly-rounded result
    float s = (float)sin((double)yaw);
    meta[i] = make_float4(dx, dy, c, s);
}

// ---------------- kernel 2: build tb = aligned.reshape(T,T,D) ----------------
// slot (b,s):  s==9 -> copy ff[b];  ts=9-s > b -> zeros;  else bilinear warp of
// ff[ts] with pose (grid_sample bilinear, zeros padding, align_corners=False).
__global__ __launch_bounds__(256) void build_tb_kernel(const float* __restrict__ ff,
                                                       const float4* __restrict__ meta,
                                                       float* __restrict__ tb) {
    int p = blockIdx.x * 256 + threadIdx.x;   // pixel index 0..HW-1
    if (p >= HW) return;
    int s = blockIdx.y, b = blockIdx.z;
    float* dst = tb + (size_t)(b*TT + s)*DD + p;

    if (s == TT - 1) {
        const float* src = ff + (size_t)b*DD + p;
        #pragma unroll
        for (int ch = 0; ch < CHN; ++ch) dst[ch*HW] = src[ch*HW];
        return;
    }
    int ts = (TT - 1) - s;
    if (ts > b) {
        #pragma unroll
        for (int ch = 0; ch < CHN; ++ch) dst[ch*HW] = 0.f;
        return;
    }
    float4 m = meta[b*9 + (ts - 1)];          // {dx, dy, cos, sin}
    int y = p / WW, x = p - y*WW;
    float xs = (2.f*(float)x + 1.f)/(float)WW - 1.f;
    float ys = (2.f*(float)y + 1.f)/(float)HH - 1.f;
    float gx =  m.z*xs + m.w*ys + m.x;
    float gy = -m.w*xs + m.z*ys + m.y;
    float ix = ((gx + 1.f)*(float)WW - 1.f)*0.5f;
    float iy = ((gy + 1.f)*(float)HH - 1.f)*0.5f;
    float ix0 = floorf(ix), iy0 = floorf(iy);
    float ix1 = ix0 + 1.f,  iy1 = iy0 + 1.f;
    float wx1 = ix - ix0, wx0 = 1.f - wx1;
    float wy1 = iy - iy0, wy0 = 1.f - wy1;

    bool inx0 = (ix0 >= 0.f) && (ix0 < (float)WW);
    bool inx1 = (ix1 >= 0.f) && (ix1 < (float)WW);
    bool iny0 = (iy0 >= 0.f) && (iy0 < (float)HH);
    bool iny1 = (iy1 >= 0.f) && (iy1 < (float)HH);
    int xi0 = min(max((int)ix0, 0), WW - 1);
    int xi1 = min(max((int)ix1, 0), WW - 1);
    int yi0 = min(max((int)iy0, 0), HH - 1);
    int yi1 = min(max((int)iy1, 0), HH - 1);

    float w00 = (inx0 && iny0) ? wx0*wy0 : 0.f;
    float w10 = (inx1 && iny0) ? wx1*wy0 : 0.f;
    float w01 = (inx0 && iny1) ? wx0*wy1 : 0.f;
    float w11 = (inx1 && iny1) ? wx1*wy1 : 0.f;
    int o00 = yi0*WW + xi0, o10 = yi0*WW + xi1;
    int o01 = yi1*WW + xi0, o11 = yi1*WW + xi1;

    const float* src = ff + (size_t)ts*DD;
    #pragma unroll
    for (int ch = 0; ch < CHN; ++ch) {
        const float* sc = src + ch*HW;
        float v = sc[o00]*w00 + sc[o10]*w10 + sc[o01]*w01 + sc[o11]*w11;
        dst[ch*HW] = v;
    }
}

// ---------------- kernel 3: Gram partials ------------------------------------
// scores[b,t,s] = dot(tb[b,t], tb[b,s]); symmetric -> 55 upper-tri accumulators.
// Split D into 33 chunks for parallelism; partial[(b,chunk),k].
__global__ __launch_bounds__(256) void gram_kernel(const float* __restrict__ tb,
                                                   float* __restrict__ partial) {
    int chunk = blockIdx.x, b = blockIdx.y;
    int tid = threadIdx.x;
    const float* base = tb + (size_t)b*TT*DD + chunk*CHUNK;

    float acc[NACC];
    #pragma unroll
    for (int k = 0; k < NACC; ++k) acc[k] = 0.f;

    for (int it = 0; it < CHUNK/256; ++it) {
        int d = it*256 + tid;
        float v[TT];
        #pragma unroll
        for (int t = 0; t < TT; ++t) v[t] = base[(size_t)t*DD + d];
        int k = 0;
        #pragma unroll
        for (int t = 0; t < TT; ++t)
            #pragma unroll
            for (int s2 = t; s2 < TT; ++s2)
                acc[k++] += v[t]*v[s2];
    }

    __shared__ float red[NACC*4];
    int lane = tid & 63, wv = tid >> 6;
    #pragma unroll
    for (int k = 0; k < NACC; ++k) {
        float a = acc[k];
        #pragma unroll
        for (int off = 32; off > 0; off >>= 1) a += __shfl_down(a, off);
        if (lane == 0) red[k*4 + wv] = a;
    }
    __syncthreads();
    if (tid < NACC) {
        float a = red[tid*4] + red[tid*4+1] + red[tid*4+2] + red[tid*4+3];
        partial[((size_t)b*NCHUNK + chunk)*NACC + tid] = a;
    }
}

// ---------------- kernel 4: softmax weights ----------------------------------
// w[b,s] = (1/T) * sum_t softmax(scores[b,t,:])[s]
__global__ void weights_kernel(const float* __restrict__ partial, float* __restrict__ w) {
    __shared__ float ws[TT*TT];
    int tid = threadIdx.x;
    if (tid < TT*TT) ws[tid] = 0.f;
    __syncthreads();
    if (tid < TT*TT) {
        int b = tid / TT, t = tid % TT;
        float sc[TT];
        for (int s = 0; s < TT; ++s) {
            int a0 = min(t, s), a1 = max(t, s);
            int k = a0*TT - a0*(a0 - 1)/2 + (a1 - a0);  // upper-tri index
            float sum = 0.f;
            for (int c = 0; c < NCHUNK; ++c)
                sum += partial[((size_t)b*NCHUNK + c)*NACC + k];
            sc[s] = sum;
        }
        float mx = sc[0];
        for (int s = 1; s < TT; ++s) mx = fmaxf(mx, sc[s]);
        float e[TT]; float den = 0.f;
        for (int s = 0; s < TT; ++s) { e[s] = expf(sc[s] - mx); den += e[s]; }
        float inv = 1.f / den;
        for (int s = 0; s < TT; ++s) atomicAdd(&ws[b*TT + s], e[s]*inv*0.1f);
    }
    __syncthreads();
    if (tid < TT*TT) w[tid] = ws[tid];
}

// ---------------- kernel 5: output -------------------------------------------
// out[b,d] = sum_s w[b,s] * tb[b,s,d]
__global__ __launch_bounds__(256) void out_kernel(const float* __restrict__ tb,
                                                  const float* __restrict__ w,
                                                  float* __restrict__ out) {
    int b = blockIdx.y;
    int d = blockIdx.x*256 + threadIdx.x;   // gridDim.x = DD/256 = 264 (exact)
    __shared__ float wl[TT];
    if (threadIdx.x < TT) wl[threadIdx.x] = w[b*TT + threadIdx.x];
    __syncthreads();
    const float* base = tb + (size_t)b*TT*DD + d;
    float acc = 0.f;
    #pragma unroll
    for (int s = 0; s < TT; ++s) acc += wl[s]*base[(size_t)s*DD];
    out[(size_t)b*DD + d] = acc;
}

extern "C" void kernel_launch(void* const* d_in, const int* in_sizes, int n_in,
                              void* d_out, int out_size, void* d_ws, size_t ws_size,
                              hipStream_t stream) {
    const float* ff = (const float*)d_in[0];   // (T, L, C) = (T, D) flat
    const float* dp = (const float*)d_in[1];   // (T, 3)
    float* out = (float*)d_out;                // (T, L, C) flat

    char* ws = (char*)d_ws;
    // layout: meta (1.4 KB) | tb (27 MB) | partial (71 KB) | w (0.4 KB)
    float4* meta   = (float4*)ws;
    float* tb      = (float*)(ws + 4096);
    float* partial = (float*)(ws + 4096 + (size_t)TT*TT*DD*sizeof(float));
    float* w       = (float*)(ws + 4096 + (size_t)TT*TT*DD*sizeof(float) + 81920);

    meta_kernel   <<<1, 128, 0, stream>>>(dp, meta);
    build_tb_kernel<<<dim3((HW + 255)/256, TT, TT), 256, 0, stream>>>(ff, meta, tb);
    gram_kernel   <<<dim3(NCHUNK, TT), 256, 0, stream>>>(tb, partial);
    weights_kernel<<<1, 128, 0, stream>>>(partial, w);
    out_kernel    <<<dim3(DD/256, TT), 256, 0, stream>>>(tb, w, out);
}